// Round 3
// baseline (320.869 us; speedup 1.0000x reference)
//
#include <hip/hip_runtime.h>

#define HW 36864      // 192*192
#define WD 192
#define BB 8
#define CC 10
#define PW 194                          // padded width (1px zero border)
#define PB ((size_t)(PW*PW*16))         // shorts per (array, b) = 602176
#define PA ((size_t)BB*PB)              // shorts per array
// ws requirement: 10 arrays * PA shorts * 2 B = 96,348,160 bytes

typedef __attribute__((ext_vector_type(8))) short short8;
typedef __attribute__((ext_vector_type(4))) float f32x4;

__device__ __forceinline__ short f2bf(float v) {
    unsigned u = __float_as_uint(v);
    unsigned r = (u + 0x7fffu + ((u >> 16) & 1u)) >> 16;   // RNE
    return (short)r;
}
__device__ __forceinline__ float b2f(short s) {
    return __uint_as_float(((unsigned)(unsigned short)s) << 16);
}

#define ASYNC16(gp, lp) __builtin_amdgcn_global_load_lds( \
    (const __attribute__((address_space(1))) void*)(gp),  \
    (__attribute__((address_space(3))) void*)(lp), 16, 0, 0)

// ---------------------------------------------------------------------------
// prep: pointwise maps (dmap/softmax, comp maps), h0 copy, and bf16 c16-packed
// padded conv-input arrays into ws:
//   arr0=h1, arr1=h2, arr2=f*att1, arr3=f*att2, arr4..7=p1..4*cmU, arr8..9=p5..6*cmL
// Two load batches forced live across asm memory fences: the compiler cannot
// sink loads past the fence into their consumers, so each wave issues 30/70
// loads back-to-back (vmcnt-deep) instead of ~3 at a time (r2 measured VGPR=52,
// 2.65 TB/s: scheduler re-sank the hoisted loads; fences bind it).
// ---------------------------------------------------------------------------
__device__ __forceinline__ void store16(short* d, const float* v, float s) {
    short8 lo, hi;
    #pragma unroll
    for (int i = 0; i < 8; ++i) lo[i] = f2bf(v[i]*s);
    hi = (short8){f2bf(v[8]*s), f2bf(v[9]*s), 0,0,0,0,0,0};
    *(short8*)d = lo;
    *(short8*)(d+8) = hi;
}

__global__ __launch_bounds__(256) void prep_kernel(
    const float* __restrict__ f_nodes, const float* __restrict__ h_nodes,
    const float* __restrict__ p_nodes,
    const float* __restrict__ w_dmap, const float* __restrict__ b_dmap,
    const float* __restrict__ w_cau, const float* __restrict__ b_cau,
    const float* __restrict__ w_cal, const float* __restrict__ b_cal,
    float* __restrict__ out, short* __restrict__ ws)
{
    int t = blockIdx.x*256 + threadIdx.x;
    if (t >= BB*PW*PW) return;
    int b  = t / (PW*PW);
    int pp = t - b*(PW*PW);
    int py = pp / PW, px = pp - py*PW;
    short* wb = ws + (size_t)b*PB + (size_t)pp*16;

    if (py == 0 || py == PW-1 || px == 0 || px == PW-1) {
        short8 z = (short8){0,0,0,0,0,0,0,0};
        #pragma unroll
        for (int a = 0; a < 10; ++a) {
            *(short8*)(wb + (size_t)a*PA)     = z;
            *(short8*)(wb + (size_t)a*PA + 8) = z;
        }
        return;
    }
    int sp = (py-1)*WD + (px-1);

    const float* f1 = f_nodes + ((size_t)(BB   + b))*CC*HW + sp;
    const float* h0 = h_nodes + ((size_t)(       b))*CC*HW + sp;
    const float* h1 = h_nodes + ((size_t)(BB   + b))*CC*HW + sp;
    const float* h2 = h_nodes + ((size_t)(2*BB + b))*CC*HW + sp;

    // ---- batch 1: f, h1, h2 (30 loads) ----
    float fv[10], av[10], bv[10];
    #pragma unroll
    for (int c = 0; c < 10; ++c) {
        fv[c] = f1[(size_t)c*HW];
        av[c] = h1[(size_t)c*HW];
        bv[c] = h2[(size_t)c*HW];
    }
    asm volatile("" ::: "memory");   // fence A: batch-1 loads all issued above

    // ---- batch 2: p1..6, h0 (70 loads) — issues under phase-1 compute ----
    float pv[6][10], h0v[10];
    #pragma unroll
    for (int k = 0; k < 6; ++k) {
        const float* p = p_nodes + ((size_t)((1+k)*BB + b))*CC*HW + sp;
        #pragma unroll
        for (int c = 0; c < 10; ++c) pv[k][c] = p[(size_t)c*HW];
    }
    #pragma unroll
    for (int c = 0; c < 10; ++c) h0v[c] = h0[(size_t)c*HW];

    const size_t O1 = (size_t)3*BB*CC*HW;
    const size_t O2 = O1 + (size_t)BB*3*HW;
    const size_t O3 = O2 + (size_t)BB*HW;

    // ---- phase-1 compute: dmap + softmax, store dmap/arr0..3 ----
    float dm[3];
    #pragma unroll
    for (int j = 0; j < 3; ++j) {
        float s = b_dmap[j];
        #pragma unroll
        for (int c = 0; c < 10; ++c) s = fmaf(w_dmap[j*30 + c],      fv[c], s);
        #pragma unroll
        for (int c = 0; c < 10; ++c) s = fmaf(w_dmap[j*30 + 10 + c], av[c], s);
        #pragma unroll
        for (int c = 0; c < 10; ++c) s = fmaf(w_dmap[j*30 + 20 + c], bv[c], s);
        dm[j] = s;
    }
    float mx = fmaxf(dm[0], fmaxf(dm[1], dm[2]));
    float e0 = expf(dm[0]-mx), e1 = expf(dm[1]-mx), e2 = expf(dm[2]-mx);
    float inv = 1.f / (e0 + e1 + e2);
    float a1 = e1*inv, a2 = e2*inv;

    #pragma unroll
    for (int j = 0; j < 3; ++j)
        out[O1 + ((size_t)b*3 + j)*HW + sp] = dm[j];

    store16(wb + 0*PA, av, 1.f);   // h1
    store16(wb + 1*PA, bv, 1.f);   // h2
    store16(wb + 2*PA, fv, a1);    // f*att1
    store16(wb + 3*PA, fv, a2);    // f*att2

    asm volatile("" ::: "memory");   // fence B: batch-2 loads all issued above

    // ---- phase-2 compute: comp maps, h0 copy, arr4..9 ----
    float su = b_cau[0];
    #pragma unroll
    for (int k = 0; k < 4; ++k)
        #pragma unroll
        for (int c = 0; c < 10; ++c) su = fmaf(w_cau[k*10 + c], pv[k][c], su);
    float cmU = 1.f / (1.f + expf(-su));

    float sl = b_cal[0];
    #pragma unroll
    for (int k = 0; k < 2; ++k)
        #pragma unroll
        for (int c = 0; c < 10; ++c) sl = fmaf(w_cal[k*10 + c], pv[4+k][c], sl);
    float cmL = 1.f / (1.f + expf(-sl));

    out[O2 + (size_t)b*HW + sp] = cmU;
    out[O3 + (size_t)b*HW + sp] = cmL;

    float* o0 = out + (size_t)b*CC*HW + sp;
    #pragma unroll
    for (int c = 0; c < 10; ++c) o0[(size_t)c*HW] = h0v[c];

    #pragma unroll
    for (int k = 0; k < 4; ++k) store16(wb + (size_t)(4+k)*PA, pv[k],   cmU);
    #pragma unroll
    for (int k = 0; k < 2; ++k) store16(wb + (size_t)(8+k)*PA, pv[4+k], cmL);
}

// ---------------------------------------------------------------------------
// half_kernel: both halves (z 0..7 upper, 8..15 lower). 16x16 px tile/block.
// Tiles DMA'd straight into LDS (18 rows x 18 px x 16ch bf16 = 648 x16B chunks,
// buffer padded to 768 chunks so 3 full 256-thread DMA rounds never spill).
// ---------------------------------------------------------------------------
__device__ __forceinline__ void dma_tile(short* lds, const short* g,
                                         int tid, int y0, int x0)
{
    #pragma unroll
    for (int r = 0; r < 3; ++r) {
        int idx = r*256 + tid;
        int row = idx / 36;               // 36 chunks (576 B) per tile row
        int col = idx - row*36;
        size_t go = (idx < 648) ? (((size_t)(y0+row)*PW + x0)*16 + (size_t)col*8)
                                : (size_t)0;
        ASYNC16(g + go, lds + (size_t)idx*8);
    }
}

__global__ __launch_bounds__(256) void half_kernel(
    const short* __restrict__ ws,
    const float* __restrict__ w_dec, const float* __restrict__ gD, const float* __restrict__ bD,
    const float* __restrict__ w_cu, const float* __restrict__ gCu, const float* __restrict__ bCu,
    const float* __restrict__ w_cl, const float* __restrict__ gCl, const float* __restrict__ bCl,
    const float* __restrict__ wg_u, const float* __restrict__ bg_u, const float* __restrict__ wc_u,
    const float* __restrict__ g_u, const float* __restrict__ be_u,
    const float* __restrict__ wg_l, const float* __restrict__ bg_l, const float* __restrict__ wc_l,
    const float* __restrict__ g_l, const float* __restrict__ be_l,
    float* __restrict__ out)
{
    __shared__ __align__(16) short sTh[6144];   // 768*8 shorts = 12288 B
    __shared__ __align__(16) short sTp0[6144];
    __shared__ __align__(16) short sTp1[6144];
    __shared__ __align__(16) short sWb[4*2688]; // 4 sets x 16 n x 168 k (pad)
    __shared__ float sMsg[256*13];
    __shared__ float sPar[302];

    const int tid  = threadIdx.x;
    const int lane = tid & 63;
    const int w    = tid >> 6;
    const int g    = lane >> 4;
    const int n    = lane & 15;
    const int half = blockIdx.z >> 3;
    const int b    = blockIdx.z & 7;
    const int x0   = blockIdx.x*16, y0 = blockIdx.y*16;

    const float* w_cmp = half ? w_cl : w_cu;
    const float* gC  = half ? gCl  : gCu;
    const float* bC  = half ? bCl  : bCu;
    const float* wg  = half ? wg_l : wg_u;
    const float* bg  = half ? bg_l : bg_u;
    const float* wc  = half ? wc_l : wc_u;
    const float* gG  = half ? g_l  : g_u;
    const float* beG = half ? be_l : be_u;
    const int nparts = half ? 2 : 4;

    const short* hArr  = ws + (size_t)half*PA     + (size_t)b*PB;
    const short* fArr  = ws + (size_t)(2+half)*PA + (size_t)b*PB;
    const short* pArr0 = ws + (size_t)(4+half*4)*PA + (size_t)b*PB;

    // zero weight LDS (pad slots must be 0), then kick off the three DMAs
    for (int i = tid; i < 4*2688/2; i += 256) ((int*)sWb)[i] = 0;
    dma_tile(sTh,  hArr,  tid, y0, x0);
    dma_tile(sTp0, fArr,  tid, y0, x0);
    dma_tile(sTp1, pArr0, tid, y0, x0);
    __syncthreads();

    // fill weights (set0=Wd_f, set1=Wd_h, set2=Wc_h, set3=Wc_p) + params
    for (int i = tid; i < 1800; i += 256) {
        int o = i/180, r = i - o*180, ci = r/9, kp = r - ci*9;
        int c  = (ci < 10) ? ci : ci - 10;
        int s2 = (ci < 10) ? 0 : 1;
        sWb[s2*2688     + o*168 + kp*16 + c] = f2bf(w_dec[i]);
        sWb[(2+s2)*2688 + o*168 + kp*16 + c] = f2bf(w_cmp[i]);
    }
    if (tid < 10) {
        sPar[tid]    = gD[tid];  sPar[10+tid] = bD[tid];
        sPar[20+tid] = gC[tid];  sPar[30+tid] = bC[tid];
        sPar[40+tid] = gG[tid];  sPar[50+tid] = beG[tid];
    }
    if (tid < 40) sPar[60+tid]  = wg[tid];
    if (tid < 2)  sPar[100+tid] = bg[tid];
    if (tid >= 56 && tid < 256) sPar[102+(tid-56)] = (tid-56 < 200) ? wc[tid-56] : 0.f;
    __syncthreads();

    // per-lane A-fragment offsets; K = kpos*16 + c, kpos 9 = dummy (0 weights)
    int aoff[5];
    #pragma unroll
    for (int t5 = 0; t5 < 5; ++t5) {
        int k  = 32*t5 + 8*g;
        int kp = k >> 4;
        int c8 = k & 15;
        if (kp < 9) { int ky = kp/3, kx = kp - ky*3; aoff[t5] = (ky*18 + kx + n)*16 + c8; }
        else        aoff[t5] = 0;
    }
    const int wbase = w*4*288;      // 288 shorts per tile row

    // B-fragments
    short8 bF[5], bH[5], bCh[5], bCp[5];
    #pragma unroll
    for (int t5 = 0; t5 < 5; ++t5) {
        int ko = 32*t5 + 8*g;
        bF[t5]  = *(const short8*)(sWb + 0*2688 + n*168 + ko);
        bH[t5]  = *(const short8*)(sWb + 1*2688 + n*168 + ko);
        bCh[t5] = *(const short8*)(sWb + 2*2688 + n*168 + ko);
        bCp[t5] = *(const short8*)(sWb + 3*2688 + n*168 + ko);
    }

    // decomp: conv(f*att, Wd_f) + conv(h, Wd_h); shared accH = conv(h, Wc_h)
    f32x4 accD[4], accH[4];
    #pragma unroll
    for (int mt = 0; mt < 4; ++mt) { accD[mt] = (f32x4){0,0,0,0}; accH[mt] = (f32x4){0,0,0,0}; }
    #pragma unroll
    for (int t5 = 0; t5 < 5; ++t5) {
        #pragma unroll
        for (int mt = 0; mt < 4; ++mt) {
            short8 a = *(const short8*)(sTp0 + wbase + mt*288 + aoff[t5]);
            accD[mt] = __builtin_amdgcn_mfma_f32_16x16x32_bf16(a, bF[t5], accD[mt], 0,0,0);
        }
    }
    #pragma unroll
    for (int t5 = 0; t5 < 5; ++t5) {
        #pragma unroll
        for (int mt = 0; mt < 4; ++mt) {
            short8 a = *(const short8*)(sTh + wbase + mt*288 + aoff[t5]);
            accD[mt] = __builtin_amdgcn_mfma_f32_16x16x32_bf16(a, bH[t5],  accD[mt], 0,0,0);
            accH[mt] = __builtin_amdgcn_mfma_f32_16x16x32_bf16(a, bCh[t5], accH[mt], 0,0,0);
        }
    }
    const int np = (n < 10) ? n : 9;
    const float gDv = sPar[np],    bDv = sPar[10+np];
    const float gCv = sPar[20+np], bCv = sPar[30+np];
    f32x4 msgf[4];
    #pragma unroll
    for (int mt = 0; mt < 4; ++mt)
        #pragma unroll
        for (int j = 0; j < 4; ++j)
            msgf[mt][j] = fmaxf(fmaf(gDv, accD[mt][j], bDv), 0.f);
    __syncthreads();   // all waves done reading sTp0 (f*att)

    // parts, double-buffered: p0 in sTp1; prefetch p_{j+1} into the freed buf
    for (int j = 0; j < nparts; ++j) {
        if (j+1 < nparts)
            dma_tile((j&1) ? sTp1 : sTp0, pArr0 + (size_t)(j+1)*PA, tid, y0, x0);
        const short* cur = (j&1) ? sTp0 : sTp1;
        f32x4 acc[4];
        #pragma unroll
        for (int mt = 0; mt < 4; ++mt) acc[mt] = (f32x4){0,0,0,0};
        #pragma unroll
        for (int t5 = 0; t5 < 5; ++t5) {
            #pragma unroll
            for (int mt = 0; mt < 4; ++mt) {
                short8 a = *(const short8*)(cur + wbase + mt*288 + aoff[t5]);
                acc[mt] = __builtin_amdgcn_mfma_f32_16x16x32_bf16(a, bCp[t5], acc[mt], 0,0,0);
            }
        }
        #pragma unroll
        for (int mt = 0; mt < 4; ++mt)
            #pragma unroll
            for (int jj = 0; jj < 4; ++jj)
                msgf[mt][jj] += fmaxf(fmaf(gCv, accH[mt][jj] + acc[mt][jj], bCv), 0.f);
        __syncthreads();   // cur fully consumed; prefetch drained
    }

    // transpose msg to [pixel][ch]
    if (n < 10) {
        #pragma unroll
        for (int mt = 0; mt < 4; ++mt)
            #pragma unroll
            for (int r2 = 0; r2 < 4; ++r2)
                sMsg[((4*w + mt)*16 + 4*g + r2)*13 + n] = msgf[mt][r2];
    }
    __syncthreads();

    // pointwise ConvGRU epilogue (fp32), one pixel/thread; h from bf16 tile
    {
        int row = tid >> 4, xx = tid & 15;
        int gy = y0 + row, gx = x0 + xx;
        float msg[10], hc[10];
        #pragma unroll
        for (int c = 0; c < 10; ++c) msg[c] = sMsg[tid*13 + c];
        #pragma unroll
        for (int c = 0; c < 10; ++c) hc[c] = b2f(sTh[((row+1)*18 + (xx+1))*16 + c]);

        float g0 = sPar[100], g1 = sPar[101];
        #pragma unroll
        for (int c = 0; c < 10; ++c) {
            g0 = fmaf(sPar[60+c], msg[c], g0);
            g1 = fmaf(sPar[80+c], msg[c], g1);
        }
        #pragma unroll
        for (int c = 0; c < 10; ++c) {
            g0 = fmaf(sPar[70+c], hc[c], g0);
            g1 = fmaf(sPar[90+c], hc[c], g1);
        }
        float r = 1.f / (1.f + expf(-g0));
        float u = 1.f / (1.f + expf(-g1));

        float* op = out + (size_t)(1+half)*BB*CC*HW + (size_t)b*CC*HW + gy*WD + gx;
        #pragma unroll
        for (int o = 0; o < 10; ++o) {
            float s = 0.f;
            const float* wr = &sPar[102 + o*20];
            #pragma unroll
            for (int c = 0; c < 10; ++c) s = fmaf(wr[c], msg[c], s);
            #pragma unroll
            for (int c = 0; c < 10; ++c) s = fmaf(wr[10+c], r*hc[c], s);
            s = fmaf(sPar[40+o], s, sPar[50+o]);
            s = (s > 0.f) ? s : 0.01f*s;
            op[(size_t)o*HW] = (1.f - u)*hc[o] + u*s;
        }
    }
}

// ---------------------------------------------------------------------------
extern "C" void kernel_launch(void* const* d_in, const int* in_sizes, int n_in,
                              void* d_out, int out_size, void* d_ws, size_t ws_size,
                              hipStream_t stream)
{
    const float* f_nodes = (const float*)d_in[0];
    const float* h_nodes = (const float*)d_in[1];
    const float* p_nodes = (const float*)d_in[2];
    const float* w_dmap   = (const float*)d_in[4];
    const float* b_dmap   = (const float*)d_in[5];
    const float* w_decomp = (const float*)d_in[6];
    const float* g_decomp = (const float*)d_in[7];
    const float* be_decomp= (const float*)d_in[8];
    const float* w_cau    = (const float*)d_in[9];
    const float* b_cau    = (const float*)d_in[10];
    const float* w_cal    = (const float*)d_in[11];
    const float* b_cal    = (const float*)d_in[12];
    const float* w_cu     = (const float*)d_in[13];
    const float* g_cu     = (const float*)d_in[14];
    const float* be_cu    = (const float*)d_in[15];
    const float* w_cl     = (const float*)d_in[16];
    const float* g_cl     = (const float*)d_in[17];
    const float* be_cl    = (const float*)d_in[18];
    const float* wg_u     = (const float*)d_in[19];
    const float* bg_u     = (const float*)d_in[20];
    const float* wc_u     = (const float*)d_in[21];
    const float* g_u      = (const float*)d_in[22];
    const float* be_u     = (const float*)d_in[23];
    const float* wg_l     = (const float*)d_in[24];
    const float* bg_l     = (const float*)d_in[25];
    const float* wc_l     = (const float*)d_in[26];
    const float* g_l      = (const float*)d_in[27];
    const float* be_l     = (const float*)d_in[28];

    float* out = (float*)d_out;
    short* ws  = (short*)d_ws;

    prep_kernel<<<dim3((BB*PW*PW + 255)/256), dim3(256), 0, stream>>>(
        f_nodes, h_nodes, p_nodes, w_dmap, b_dmap,
        w_cau, b_cau, w_cal, b_cal, out, ws);

    half_kernel<<<dim3(WD/16, WD/16, 16), dim3(256), 0, stream>>>(
        ws, w_decomp, g_decomp, be_decomp,
        w_cu, g_cu, be_cu, w_cl, g_cl, be_cl,
        wg_u, bg_u, wc_u, g_u, be_u,
        wg_l, bg_l, wc_l, g_l, be_l,
        out);
}

// Round 7
// 314.351 us; speedup vs baseline: 1.0207x; 1.0207x over previous
//
#include <hip/hip_runtime.h>

#define HW 36864      // 192*192
#define WD 192
#define BB 8
#define CC 10
#define PW 194                          // padded width (1px zero border)
#define PB ((size_t)(PW*PW*16))         // shorts per (array, b) = 602176
#define PA ((size_t)BB*PB)              // shorts per array
// ws requirement: 10 arrays * PA shorts * 2 B = 96,348,160 bytes

typedef __attribute__((ext_vector_type(8))) short short8;
typedef __attribute__((ext_vector_type(4))) float f32x4;

__device__ __forceinline__ short f2bf(float v) {
    unsigned u = __float_as_uint(v);
    unsigned r = (u + 0x7fffu + ((u >> 16) & 1u)) >> 16;   // RNE
    return (short)r;
}
__device__ __forceinline__ float b2f(short s) {
    return __uint_as_float(((unsigned)(unsigned short)s) << 16);
}

#define ASYNC16(gp, lp) __builtin_amdgcn_global_load_lds( \
    (const __attribute__((address_space(1))) void*)(gp),  \
    (__attribute__((address_space(3))) void*)(lp), 16, 0, 0)

// Forced-order global load: asm volatile preserves emission order, so all 100
// loads issue back-to-back (vmcnt-deep, HW cap 63/wave) instead of the ~3/wave
// the scheduler otherwise leaves in flight (r0-r3: VGPR 40-52, 2.6 TB/s).
#define GLOAD(dst, ptr) asm volatile("global_load_dword %0, %1, off" \
    : "=v"(dst) : "v"(ptr))

// ---------------------------------------------------------------------------
// prep: pointwise maps (dmap/softmax, comp maps), h0 copy, and bf16 c16-packed
// padded conv-input arrays into ws:
//   arr0=h1, arr1=h2, arr2=f*att1, arr3=f*att2, arr4..7=p1..4*cmU, arr8..9=p5..6*cmL
// ---------------------------------------------------------------------------
__device__ __forceinline__ void store16(short* d, const float* v, float s) {
    short8 lo, hi;
    #pragma unroll
    for (int i = 0; i < 8; ++i) lo[i] = f2bf(v[i]*s);
    hi = (short8){f2bf(v[8]*s), f2bf(v[9]*s), 0,0,0,0,0,0};
    *(short8*)d = lo;
    *(short8*)(d+8) = hi;
}

__global__ __launch_bounds__(256) void prep_kernel(
    const float* __restrict__ f_nodes, const float* __restrict__ h_nodes,
    const float* __restrict__ p_nodes,
    const float* __restrict__ w_dmap, const float* __restrict__ b_dmap,
    const float* __restrict__ w_cau, const float* __restrict__ b_cau,
    const float* __restrict__ w_cal, const float* __restrict__ b_cal,
    float* __restrict__ out, short* __restrict__ ws)
{
    int t = blockIdx.x*256 + threadIdx.x;
    if (t >= BB*PW*PW) return;
    int b  = t / (PW*PW);
    int pp = t - b*(PW*PW);
    int py = pp / PW, px = pp - py*PW;
    short* wb = ws + (size_t)b*PB + (size_t)pp*16;

    if (py == 0 || py == PW-1 || px == 0 || px == PW-1) {
        short8 z = (short8){0,0,0,0,0,0,0,0};
        #pragma unroll
        for (int a = 0; a < 10; ++a) {
            *(short8*)(wb + (size_t)a*PA)     = z;
            *(short8*)(wb + (size_t)a*PA + 8) = z;
        }
        return;
    }
    int sp = (py-1)*WD + (px-1);

    const float* f1 = f_nodes + ((size_t)(BB   + b))*CC*HW + sp;
    const float* h0 = h_nodes + ((size_t)(       b))*CC*HW + sp;
    const float* h1 = h_nodes + ((size_t)(BB   + b))*CC*HW + sp;
    const float* h2 = h_nodes + ((size_t)(2*BB + b))*CC*HW + sp;

    // ---- forced load batch: all 100 inputs issued in asm order ----
    float fv[10], av[10], bv[10], h0v[10], pv[6][10];
    #pragma unroll
    for (int c = 0; c < 10; ++c) GLOAD(fv[c], f1 + (size_t)c*HW);
    #pragma unroll
    for (int c = 0; c < 10; ++c) GLOAD(av[c], h1 + (size_t)c*HW);
    #pragma unroll
    for (int c = 0; c < 10; ++c) GLOAD(bv[c], h2 + (size_t)c*HW);
    #pragma unroll
    for (int k = 0; k < 6; ++k) {
        const float* p = p_nodes + ((size_t)((1+k)*BB + b))*CC*HW + sp;
        #pragma unroll
        for (int c = 0; c < 10; ++c) GLOAD(pv[k][c], p + (size_t)c*HW);
    }
    #pragma unroll
    for (int c = 0; c < 10; ++c) GLOAD(h0v[c], h0 + (size_t)c*HW);

    asm volatile("s_waitcnt vmcnt(0)" ::: "memory");
    __builtin_amdgcn_sched_barrier(0);      // rule #18: consumers stay below

    const size_t O1 = (size_t)3*BB*CC*HW;
    const size_t O2 = O1 + (size_t)BB*3*HW;
    const size_t O3 = O2 + (size_t)BB*HW;

    // ---- compute + stores (proven r0 path) ----
    float dm[3];
    #pragma unroll
    for (int j = 0; j < 3; ++j) {
        float s = b_dmap[j];
        #pragma unroll
        for (int c = 0; c < 10; ++c) s = fmaf(w_dmap[j*30 + c],      fv[c], s);
        #pragma unroll
        for (int c = 0; c < 10; ++c) s = fmaf(w_dmap[j*30 + 10 + c], av[c], s);
        #pragma unroll
        for (int c = 0; c < 10; ++c) s = fmaf(w_dmap[j*30 + 20 + c], bv[c], s);
        dm[j] = s;
        out[O1 + ((size_t)b*3 + j)*HW + sp] = s;
    }
    float mx = fmaxf(dm[0], fmaxf(dm[1], dm[2]));
    float e0 = expf(dm[0]-mx), e1 = expf(dm[1]-mx), e2 = expf(dm[2]-mx);
    float inv = 1.f / (e0 + e1 + e2);
    float a1 = e1*inv, a2 = e2*inv;

    store16(wb + 0*PA, av, 1.f);   // h1
    store16(wb + 1*PA, bv, 1.f);   // h2
    store16(wb + 2*PA, fv, a1);    // f*att1
    store16(wb + 3*PA, fv, a2);    // f*att2

    // h0 copy to out slot 0
    float* o0 = out + (size_t)b*CC*HW + sp;
    #pragma unroll
    for (int c = 0; c < 10; ++c) o0[(size_t)c*HW] = h0v[c];

    // upper parts
    {
        float su = b_cau[0];
        #pragma unroll
        for (int k = 0; k < 4; ++k)
            #pragma unroll
            for (int c = 0; c < 10; ++c) su = fmaf(w_cau[k*10 + c], pv[k][c], su);
        float cmU = 1.f / (1.f + expf(-su));
        out[O2 + (size_t)b*HW + sp] = cmU;
        #pragma unroll
        for (int k = 0; k < 4; ++k) store16(wb + (size_t)(4+k)*PA, pv[k], cmU);
    }
    // lower parts
    {
        float sl = b_cal[0];
        #pragma unroll
        for (int k = 0; k < 2; ++k)
            #pragma unroll
            for (int c = 0; c < 10; ++c) sl = fmaf(w_cal[k*10 + c], pv[4+k][c], sl);
        float cmL = 1.f / (1.f + expf(-sl));
        out[O3 + (size_t)b*HW + sp] = cmL;
        #pragma unroll
        for (int k = 0; k < 2; ++k) store16(wb + (size_t)(8+k)*PA, pv[4+k], cmL);
    }
}

// ---------------------------------------------------------------------------
// half_kernel: both halves (z 0..7 upper, 8..15 lower). 16x16 px tile/block.
// Tiles DMA'd straight into LDS (18 rows x 18 px x 16ch bf16 = 648 x16B chunks,
// buffer padded to 768 chunks so 3 full 256-thread DMA rounds never spill).
// ---------------------------------------------------------------------------
__device__ __forceinline__ void dma_tile(short* lds, const short* g,
                                         int tid, int y0, int x0)
{
    #pragma unroll
    for (int r = 0; r < 3; ++r) {
        int idx = r*256 + tid;
        int row = idx / 36;               // 36 chunks (576 B) per tile row
        int col = idx - row*36;
        size_t go = (idx < 648) ? (((size_t)(y0+row)*PW + x0)*16 + (size_t)col*8)
                                : (size_t)0;
        ASYNC16(g + go, lds + (size_t)idx*8);
    }
}

__global__ __launch_bounds__(256) void half_kernel(
    const short* __restrict__ ws,
    const float* __restrict__ w_dec, const float* __restrict__ gD, const float* __restrict__ bD,
    const float* __restrict__ w_cu, const float* __restrict__ gCu, const float* __restrict__ bCu,
    const float* __restrict__ w_cl, const float* __restrict__ gCl, const float* __restrict__ bCl,
    const float* __restrict__ wg_u, const float* __restrict__ bg_u, const float* __restrict__ wc_u,
    const float* __restrict__ g_u, const float* __restrict__ be_u,
    const float* __restrict__ wg_l, const float* __restrict__ bg_l, const float* __restrict__ wc_l,
    const float* __restrict__ g_l, const float* __restrict__ be_l,
    float* __restrict__ out)
{
    __shared__ __align__(16) short sTh[6144];   // 768*8 shorts = 12288 B
    __shared__ __align__(16) short sTp0[6144];
    __shared__ __align__(16) short sTp1[6144];
    __shared__ __align__(16) short sWb[4*2688]; // 4 sets x 16 n x 168 k (pad)
    __shared__ float sMsg[256*13];
    __shared__ float sPar[302];

    const int tid  = threadIdx.x;
    const int lane = tid & 63;
    const int w    = tid >> 6;
    const int g    = lane >> 4;
    const int n    = lane & 15;
    const int half = blockIdx.z >> 3;
    const int b    = blockIdx.z & 7;
    const int x0   = blockIdx.x*16, y0 = blockIdx.y*16;

    const float* w_cmp = half ? w_cl : w_cu;
    const float* gC  = half ? gCl  : gCu;
    const float* bC  = half ? bCl  : bCu;
    const float* wg  = half ? wg_l : wg_u;
    const float* bg  = half ? bg_l : bg_u;
    const float* wc  = half ? wc_l : wc_u;
    const float* gG  = half ? g_l  : g_u;
    const float* beG = half ? be_l : be_u;
    const int nparts = half ? 2 : 4;

    const short* hArr  = ws + (size_t)half*PA     + (size_t)b*PB;
    const short* fArr  = ws + (size_t)(2+half)*PA + (size_t)b*PB;
    const short* pArr0 = ws + (size_t)(4+half*4)*PA + (size_t)b*PB;

    // zero weight LDS (pad slots must be 0), then kick off the three DMAs
    for (int i = tid; i < 4*2688/2; i += 256) ((int*)sWb)[i] = 0;
    dma_tile(sTh,  hArr,  tid, y0, x0);
    dma_tile(sTp0, fArr,  tid, y0, x0);
    dma_tile(sTp1, pArr0, tid, y0, x0);
    __syncthreads();

    // fill weights (set0=Wd_f, set1=Wd_h, set2=Wc_h, set3=Wc_p) + params
    for (int i = tid; i < 1800; i += 256) {
        int o = i/180, r = i - o*180, ci = r/9, kp = r - ci*9;
        int c  = (ci < 10) ? ci : ci - 10;
        int s2 = (ci < 10) ? 0 : 1;
        sWb[s2*2688     + o*168 + kp*16 + c] = f2bf(w_dec[i]);
        sWb[(2+s2)*2688 + o*168 + kp*16 + c] = f2bf(w_cmp[i]);
    }
    if (tid < 10) {
        sPar[tid]    = gD[tid];  sPar[10+tid] = bD[tid];
        sPar[20+tid] = gC[tid];  sPar[30+tid] = bC[tid];
        sPar[40+tid] = gG[tid];  sPar[50+tid] = beG[tid];
    }
    if (tid < 40) sPar[60+tid]  = wg[tid];
    if (tid < 2)  sPar[100+tid] = bg[tid];
    if (tid >= 56 && tid < 256) sPar[102+(tid-56)] = (tid-56 < 200) ? wc[tid-56] : 0.f;
    __syncthreads();

    // per-lane A-fragment offsets; K = kpos*16 + c, kpos 9 = dummy (0 weights)
    int aoff[5];
    #pragma unroll
    for (int t5 = 0; t5 < 5; ++t5) {
        int k  = 32*t5 + 8*g;
        int kp = k >> 4;
        int c8 = k & 15;
        if (kp < 9) { int ky = kp/3, kx = kp - ky*3; aoff[t5] = (ky*18 + kx + n)*16 + c8; }
        else        aoff[t5] = 0;
    }
    const int wbase = w*4*288;      // 288 shorts per tile row

    // B-fragments
    short8 bF[5], bH[5], bCh[5], bCp[5];
    #pragma unroll
    for (int t5 = 0; t5 < 5; ++t5) {
        int ko = 32*t5 + 8*g;
        bF[t5]  = *(const short8*)(sWb + 0*2688 + n*168 + ko);
        bH[t5]  = *(const short8*)(sWb + 1*2688 + n*168 + ko);
        bCh[t5] = *(const short8*)(sWb + 2*2688 + n*168 + ko);
        bCp[t5] = *(const short8*)(sWb + 3*2688 + n*168 + ko);
    }

    // decomp: conv(f*att, Wd_f) + conv(h, Wd_h); shared accH = conv(h, Wc_h)
    f32x4 accD[4], accH[4];
    #pragma unroll
    for (int mt = 0; mt < 4; ++mt) { accD[mt] = (f32x4){0,0,0,0}; accH[mt] = (f32x4){0,0,0,0}; }
    #pragma unroll
    for (int t5 = 0; t5 < 5; ++t5) {
        #pragma unroll
        for (int mt = 0; mt < 4; ++mt) {
            short8 a = *(const short8*)(sTp0 + wbase + mt*288 + aoff[t5]);
            accD[mt] = __builtin_amdgcn_mfma_f32_16x16x32_bf16(a, bF[t5], accD[mt], 0,0,0);
        }
    }
    #pragma unroll
    for (int t5 = 0; t5 < 5; ++t5) {
        #pragma unroll
        for (int mt = 0; mt < 4; ++mt) {
            short8 a = *(const short8*)(sTh + wbase + mt*288 + aoff[t5]);
            accD[mt] = __builtin_amdgcn_mfma_f32_16x16x32_bf16(a, bH[t5],  accD[mt], 0,0,0);
            accH[mt] = __builtin_amdgcn_mfma_f32_16x16x32_bf16(a, bCh[t5], accH[mt], 0,0,0);
        }
    }
    const int np = (n < 10) ? n : 9;
    const float gDv = sPar[np],    bDv = sPar[10+np];
    const float gCv = sPar[20+np], bCv = sPar[30+np];
    f32x4 msgf[4];
    #pragma unroll
    for (int mt = 0; mt < 4; ++mt)
        #pragma unroll
        for (int j = 0; j < 4; ++j)
            msgf[mt][j] = fmaxf(fmaf(gDv, accD[mt][j], bDv), 0.f);
    __syncthreads();   // all waves done reading sTp0 (f*att)

    // parts, double-buffered: p0 in sTp1; prefetch p_{j+1} into the freed buf
    for (int j = 0; j < nparts; ++j) {
        if (j+1 < nparts)
            dma_tile((j&1) ? sTp1 : sTp0, pArr0 + (size_t)(j+1)*PA, tid, y0, x0);
        const short* cur = (j&1) ? sTp0 : sTp1;
        f32x4 acc[4];
        #pragma unroll
        for (int mt = 0; mt < 4; ++mt) acc[mt] = (f32x4){0,0,0,0};
        #pragma unroll
        for (int t5 = 0; t5 < 5; ++t5) {
            #pragma unroll
            for (int mt = 0; mt < 4; ++mt) {
                short8 a = *(const short8*)(cur + wbase + mt*288 + aoff[t5]);
                acc[mt] = __builtin_amdgcn_mfma_f32_16x16x32_bf16(a, bCp[t5], acc[mt], 0,0,0);
            }
        }
        #pragma unroll
        for (int mt = 0; mt < 4; ++mt)
            #pragma unroll
            for (int jj = 0; jj < 4; ++jj)
                msgf[mt][jj] += fmaxf(fmaf(gCv, accH[mt][jj] + acc[mt][jj], bCv), 0.f);
        __syncthreads();   // cur fully consumed; prefetch drained
    }

    // transpose msg to [pixel][ch]
    if (n < 10) {
        #pragma unroll
        for (int mt = 0; mt < 4; ++mt)
            #pragma unroll
            for (int r2 = 0; r2 < 4; ++r2)
                sMsg[((4*w + mt)*16 + 4*g + r2)*13 + n] = msgf[mt][r2];
    }
    __syncthreads();

    // pointwise ConvGRU epilogue (fp32), one pixel/thread; h from bf16 tile
    {
        int row = tid >> 4, xx = tid & 15;
        int gy = y0 + row, gx = x0 + xx;
        float msg[10], hc[10];
        #pragma unroll
        for (int c = 0; c < 10; ++c) msg[c] = sMsg[tid*13 + c];
        #pragma unroll
        for (int c = 0; c < 10; ++c) hc[c] = b2f(sTh[((row+1)*18 + (xx+1))*16 + c]);

        float g0 = sPar[100], g1 = sPar[101];
        #pragma unroll
        for (int c = 0; c < 10; ++c) {
            g0 = fmaf(sPar[60+c], msg[c], g0);
            g1 = fmaf(sPar[80+c], msg[c], g1);
        }
        #pragma unroll
        for (int c = 0; c < 10; ++c) {
            g0 = fmaf(sPar[70+c], hc[c], g0);
            g1 = fmaf(sPar[90+c], hc[c], g1);
        }
        float r = 1.f / (1.f + expf(-g0));
        float u = 1.f / (1.f + expf(-g1));

        float* op = out + (size_t)(1+half)*BB*CC*HW + (size_t)b*CC*HW + gy*WD + gx;
        #pragma unroll
        for (int o = 0; o < 10; ++o) {
            float s = 0.f;
            const float* wr = &sPar[102 + o*20];
            #pragma unroll
            for (int c = 0; c < 10; ++c) s = fmaf(wr[c], msg[c], s);
            #pragma unroll
            for (int c = 0; c < 10; ++c) s = fmaf(wr[10+c], r*hc[c], s);
            s = fmaf(sPar[40+o], s, sPar[50+o]);
            s = (s > 0.f) ? s : 0.01f*s;
            op[(size_t)o*HW] = (1.f - u)*hc[o] + u*s;
        }
    }
}

// ---------------------------------------------------------------------------
extern "C" void kernel_launch(void* const* d_in, const int* in_sizes, int n_in,
                              void* d_out, int out_size, void* d_ws, size_t ws_size,
                              hipStream_t stream)
{
    const float* f_nodes = (const float*)d_in[0];
    const float* h_nodes = (const float*)d_in[1];
    const float* p_nodes = (const float*)d_in[2];
    const float* w_dmap   = (const float*)d_in[4];
    const float* b_dmap   = (const float*)d_in[5];
    const float* w_decomp = (const float*)d_in[6];
    const float* g_decomp = (const float*)d_in[7];
    const float* be_decomp= (const float*)d_in[8];
    const float* w_cau    = (const float*)d_in[9];
    const float* b_cau    = (const float*)d_in[10];
    const float* w_cal    = (const float*)d_in[11];
    const float* b_cal    = (const float*)d_in[12];
    const float* w_cu     = (const float*)d_in[13];
    const float* g_cu     = (const float*)d_in[14];
    const float* be_cu    = (const float*)d_in[15];
    const float* w_cl     = (const float*)d_in[16];
    const float* g_cl     = (const float*)d_in[17];
    const float* be_cl    = (const float*)d_in[18];
    const float* wg_u     = (const float*)d_in[19];
    const float* bg_u     = (const float*)d_in[20];
    const float* wc_u     = (const float*)d_in[21];
    const float* g_u      = (const float*)d_in[22];
    const float* be_u     = (const float*)d_in[23];
    const float* wg_l     = (const float*)d_in[24];
    const float* bg_l     = (const float*)d_in[25];
    const float* wc_l     = (const float*)d_in[26];
    const float* g_l      = (const float*)d_in[27];
    const float* be_l     = (const float*)d_in[28];

    float* out = (float*)d_out;
    short* ws  = (short*)d_ws;

    prep_kernel<<<dim3((BB*PW*PW + 255)/256), dim3(256), 0, stream>>>(
        f_nodes, h_nodes, p_nodes, w_dmap, b_dmap,
        w_cau, b_cau, w_cal, b_cal, out, ws);

    half_kernel<<<dim3(WD/16, WD/16, 16), dim3(256), 0, stream>>>(
        ws, w_decomp, g_decomp, be_decomp,
        w_cu, g_cu, be_cu, w_cl, g_cl, be_cl,
        wg_u, bg_u, wc_u, g_u, be_u,
        wg_l, bg_l, wc_l, g_l, be_l,
        out);
}

// Round 8
// 310.221 us; speedup vs baseline: 1.0343x; 1.0133x over previous
//
#include <hip/hip_runtime.h>

#define HW 36864      // 192*192
#define WD 192
#define BB 8
#define CC 10
#define PW 194                          // padded width (1px zero border)
#define PB ((size_t)(PW*PW*16))         // shorts per (array, b) = 602176
#define PA ((size_t)BB*PB)              // shorts per array
#define NA (BB*PW*PW)                   // pixels (incl. pad ring) = 301088
// ws requirement: 10 arrays * PA shorts * 2 B = 96,348,160 bytes

typedef __attribute__((ext_vector_type(8))) short short8;
typedef __attribute__((ext_vector_type(4))) float f32x4;

__device__ __forceinline__ short f2bf(float v) {
    unsigned u = __float_as_uint(v);
    unsigned r = (u + 0x7fffu + ((u >> 16) & 1u)) >> 16;   // RNE
    return (short)r;
}
__device__ __forceinline__ float b2f(short s) {
    return __uint_as_float(((unsigned)(unsigned short)s) << 16);
}

#define ASYNC16(gp, lp) __builtin_amdgcn_global_load_lds( \
    (const __attribute__((address_space(1))) void*)(gp),  \
    (__attribute__((address_space(3))) void*)(lp), 16, 0, 0)

// ---------------------------------------------------------------------------
// prep (role-split): BW tracks resident waves (r0/r1/r7 evidence), and the
// 1-thread/px grid caps at 4.6 blocks/CU (~30% occupancy). Split each pixel
// across 3 threads by input stream — role 0: f/h1/h2/h0 -> dmap/att/arr0-3/h0;
// role 1: p1-4 -> cmU/arr4-7; role 2: p5-6 -> cmL/arr8-9. No duplicated reads,
// same writes, proven math per role, 3x the waves (3529 blocks).
//   arr0=h1, arr1=h2, arr2=f*att1, arr3=f*att2, arr4..7=p1..4*cmU, arr8..9=p5..6*cmL
// ---------------------------------------------------------------------------
__device__ __forceinline__ void store16(short* d, const float* v, float s) {
    short8 lo, hi;
    #pragma unroll
    for (int i = 0; i < 8; ++i) lo[i] = f2bf(v[i]*s);
    hi = (short8){f2bf(v[8]*s), f2bf(v[9]*s), 0,0,0,0,0,0};
    *(short8*)d = lo;
    *(short8*)(d+8) = hi;
}

__global__ __launch_bounds__(256) void prep_kernel(
    const float* __restrict__ f_nodes, const float* __restrict__ h_nodes,
    const float* __restrict__ p_nodes,
    const float* __restrict__ w_dmap, const float* __restrict__ b_dmap,
    const float* __restrict__ w_cau, const float* __restrict__ b_cau,
    const float* __restrict__ w_cal, const float* __restrict__ b_cal,
    float* __restrict__ out, short* __restrict__ ws)
{
    int t = blockIdx.x*256 + threadIdx.x;
    if (t >= 3*NA) return;
    int role = t / NA;
    int pb   = t - role*NA;
    int b  = pb / (PW*PW);
    int pp = pb - b*(PW*PW);
    int py = pp / PW, px = pp - py*PW;
    short* wb = ws + (size_t)b*PB + (size_t)pp*16;

    const int a0 = (role == 0) ? 0 : (role == 1) ? 4 : 8;   // first ws array
    const int na = (role == 0) ? 4 : (role == 1) ? 4 : 2;   // arrays this role

    if (py == 0 || py == PW-1 || px == 0 || px == PW-1) {
        short8 z = (short8){0,0,0,0,0,0,0,0};
        for (int a = a0; a < a0+na; ++a) {
            *(short8*)(wb + (size_t)a*PA)     = z;
            *(short8*)(wb + (size_t)a*PA + 8) = z;
        }
        return;
    }
    int sp = (py-1)*WD + (px-1);

    const size_t O1 = (size_t)3*BB*CC*HW;
    const size_t O2 = O1 + (size_t)BB*3*HW;
    const size_t O3 = O2 + (size_t)BB*HW;

    if (role == 0) {
        // ---- f, h1, h2, h0: dmap + softmax, arr0-3, h0 copy ----
        const float* f1 = f_nodes + ((size_t)(BB   + b))*CC*HW + sp;
        const float* h0 = h_nodes + ((size_t)(       b))*CC*HW + sp;
        const float* h1 = h_nodes + ((size_t)(BB   + b))*CC*HW + sp;
        const float* h2 = h_nodes + ((size_t)(2*BB + b))*CC*HW + sp;

        float fv[10], av[10], bv[10], h0v[10];
        #pragma unroll
        for (int c = 0; c < 10; ++c) {
            fv[c]  = f1[(size_t)c*HW];
            av[c]  = h1[(size_t)c*HW];
            bv[c]  = h2[(size_t)c*HW];
            h0v[c] = h0[(size_t)c*HW];
        }

        float dm[3];
        #pragma unroll
        for (int j = 0; j < 3; ++j) {
            float s = b_dmap[j];
            #pragma unroll
            for (int c = 0; c < 10; ++c) s = fmaf(w_dmap[j*30 + c],      fv[c], s);
            #pragma unroll
            for (int c = 0; c < 10; ++c) s = fmaf(w_dmap[j*30 + 10 + c], av[c], s);
            #pragma unroll
            for (int c = 0; c < 10; ++c) s = fmaf(w_dmap[j*30 + 20 + c], bv[c], s);
            dm[j] = s;
            out[O1 + ((size_t)b*3 + j)*HW + sp] = s;
        }
        float mx = fmaxf(dm[0], fmaxf(dm[1], dm[2]));
        float e0 = expf(dm[0]-mx), e1 = expf(dm[1]-mx), e2 = expf(dm[2]-mx);
        float inv = 1.f / (e0 + e1 + e2);
        float a1 = e1*inv, a2 = e2*inv;

        store16(wb + 0*PA, av, 1.f);   // h1
        store16(wb + 1*PA, bv, 1.f);   // h2
        store16(wb + 2*PA, fv, a1);    // f*att1
        store16(wb + 3*PA, fv, a2);    // f*att2

        float* o0 = out + (size_t)b*CC*HW + sp;
        #pragma unroll
        for (int c = 0; c < 10; ++c) o0[(size_t)c*HW] = h0v[c];
    } else if (role == 1) {
        // ---- p1..4: cmU, arr4-7 ----
        float pv[4][10];
        float su = b_cau[0];
        #pragma unroll
        for (int k = 0; k < 4; ++k) {
            const float* p = p_nodes + ((size_t)((1+k)*BB + b))*CC*HW + sp;
            #pragma unroll
            for (int c = 0; c < 10; ++c) pv[k][c] = p[(size_t)c*HW];
            #pragma unroll
            for (int c = 0; c < 10; ++c) su = fmaf(w_cau[k*10 + c], pv[k][c], su);
        }
        float cmU = 1.f / (1.f + expf(-su));
        out[O2 + (size_t)b*HW + sp] = cmU;
        #pragma unroll
        for (int k = 0; k < 4; ++k) store16(wb + (size_t)(4+k)*PA, pv[k], cmU);
    } else {
        // ---- p5..6: cmL, arr8-9 ----
        float qv[2][10];
        float sl = b_cal[0];
        #pragma unroll
        for (int k = 0; k < 2; ++k) {
            const float* p = p_nodes + ((size_t)((5+k)*BB + b))*CC*HW + sp;
            #pragma unroll
            for (int c = 0; c < 10; ++c) qv[k][c] = p[(size_t)c*HW];
            #pragma unroll
            for (int c = 0; c < 10; ++c) sl = fmaf(w_cal[k*10 + c], qv[k][c], sl);
        }
        float cmL = 1.f / (1.f + expf(-sl));
        out[O3 + (size_t)b*HW + sp] = cmL;
        #pragma unroll
        for (int k = 0; k < 2; ++k) store16(wb + (size_t)(8+k)*PA, qv[k], cmL);
    }
}

// ---------------------------------------------------------------------------
// half_kernel: both halves (z 0..7 upper, 8..15 lower). 16x16 px tile/block.
// Tiles DMA'd straight into LDS (18 rows x 18 px x 16ch bf16 = 648 x16B chunks,
// buffer padded to 768 chunks so 3 full 256-thread DMA rounds never spill).
// ---------------------------------------------------------------------------
__device__ __forceinline__ void dma_tile(short* lds, const short* g,
                                         int tid, int y0, int x0)
{
    #pragma unroll
    for (int r = 0; r < 3; ++r) {
        int idx = r*256 + tid;
        int row = idx / 36;               // 36 chunks (576 B) per tile row
        int col = idx - row*36;
        size_t go = (idx < 648) ? (((size_t)(y0+row)*PW + x0)*16 + (size_t)col*8)
                                : (size_t)0;
        ASYNC16(g + go, lds + (size_t)idx*8);
    }
}

__global__ __launch_bounds__(256) void half_kernel(
    const short* __restrict__ ws,
    const float* __restrict__ w_dec, const float* __restrict__ gD, const float* __restrict__ bD,
    const float* __restrict__ w_cu, const float* __restrict__ gCu, const float* __restrict__ bCu,
    const float* __restrict__ w_cl, const float* __restrict__ gCl, const float* __restrict__ bCl,
    const float* __restrict__ wg_u, const float* __restrict__ bg_u, const float* __restrict__ wc_u,
    const float* __restrict__ g_u, const float* __restrict__ be_u,
    const float* __restrict__ wg_l, const float* __restrict__ bg_l, const float* __restrict__ wc_l,
    const float* __restrict__ g_l, const float* __restrict__ be_l,
    float* __restrict__ out)
{
    __shared__ __align__(16) short sTh[6144];   // 768*8 shorts = 12288 B
    __shared__ __align__(16) short sTp0[6144];
    __shared__ __align__(16) short sTp1[6144];
    __shared__ __align__(16) short sWb[4*2688]; // 4 sets x 16 n x 168 k (pad)
    __shared__ float sMsg[256*13];
    __shared__ float sPar[302];

    const int tid  = threadIdx.x;
    const int lane = tid & 63;
    const int w    = tid >> 6;
    const int g    = lane >> 4;
    const int n    = lane & 15;
    const int half = blockIdx.z >> 3;
    const int b    = blockIdx.z & 7;
    const int x0   = blockIdx.x*16, y0 = blockIdx.y*16;

    const float* w_cmp = half ? w_cl : w_cu;
    const float* gC  = half ? gCl  : gCu;
    const float* bC  = half ? bCl  : bCu;
    const float* wg  = half ? wg_l : wg_u;
    const float* bg  = half ? bg_l : bg_u;
    const float* wc  = half ? wc_l : wc_u;
    const float* gG  = half ? g_l  : g_u;
    const float* beG = half ? be_l : be_u;
    const int nparts = half ? 2 : 4;

    const short* hArr  = ws + (size_t)half*PA     + (size_t)b*PB;
    const short* fArr  = ws + (size_t)(2+half)*PA + (size_t)b*PB;
    const short* pArr0 = ws + (size_t)(4+half*4)*PA + (size_t)b*PB;

    // zero weight LDS (pad slots must be 0), then kick off the three DMAs
    for (int i = tid; i < 4*2688/2; i += 256) ((int*)sWb)[i] = 0;
    dma_tile(sTh,  hArr,  tid, y0, x0);
    dma_tile(sTp0, fArr,  tid, y0, x0);
    dma_tile(sTp1, pArr0, tid, y0, x0);
    __syncthreads();

    // fill weights (set0=Wd_f, set1=Wd_h, set2=Wc_h, set3=Wc_p) + params
    for (int i = tid; i < 1800; i += 256) {
        int o = i/180, r = i - o*180, ci = r/9, kp = r - ci*9;
        int c  = (ci < 10) ? ci : ci - 10;
        int s2 = (ci < 10) ? 0 : 1;
        sWb[s2*2688     + o*168 + kp*16 + c] = f2bf(w_dec[i]);
        sWb[(2+s2)*2688 + o*168 + kp*16 + c] = f2bf(w_cmp[i]);
    }
    if (tid < 10) {
        sPar[tid]    = gD[tid];  sPar[10+tid] = bD[tid];
        sPar[20+tid] = gC[tid];  sPar[30+tid] = bC[tid];
        sPar[40+tid] = gG[tid];  sPar[50+tid] = beG[tid];
    }
    if (tid < 40) sPar[60+tid]  = wg[tid];
    if (tid < 2)  sPar[100+tid] = bg[tid];
    if (tid >= 56 && tid < 256) sPar[102+(tid-56)] = (tid-56 < 200) ? wc[tid-56] : 0.f;
    __syncthreads();

    // per-lane A-fragment offsets; K = kpos*16 + c, kpos 9 = dummy (0 weights)
    int aoff[5];
    #pragma unroll
    for (int t5 = 0; t5 < 5; ++t5) {
        int k  = 32*t5 + 8*g;
        int kp = k >> 4;
        int c8 = k & 15;
        if (kp < 9) { int ky = kp/3, kx = kp - ky*3; aoff[t5] = (ky*18 + kx + n)*16 + c8; }
        else        aoff[t5] = 0;
    }
    const int wbase = w*4*288;      // 288 shorts per tile row

    // B-fragments
    short8 bF[5], bH[5], bCh[5], bCp[5];
    #pragma unroll
    for (int t5 = 0; t5 < 5; ++t5) {
        int ko = 32*t5 + 8*g;
        bF[t5]  = *(const short8*)(sWb + 0*2688 + n*168 + ko);
        bH[t5]  = *(const short8*)(sWb + 1*2688 + n*168 + ko);
        bCh[t5] = *(const short8*)(sWb + 2*2688 + n*168 + ko);
        bCp[t5] = *(const short8*)(sWb + 3*2688 + n*168 + ko);
    }

    // decomp: conv(f*att, Wd_f) + conv(h, Wd_h); shared accH = conv(h, Wc_h)
    f32x4 accD[4], accH[4];
    #pragma unroll
    for (int mt = 0; mt < 4; ++mt) { accD[mt] = (f32x4){0,0,0,0}; accH[mt] = (f32x4){0,0,0,0}; }
    #pragma unroll
    for (int t5 = 0; t5 < 5; ++t5) {
        #pragma unroll
        for (int mt = 0; mt < 4; ++mt) {
            short8 a = *(const short8*)(sTp0 + wbase + mt*288 + aoff[t5]);
            accD[mt] = __builtin_amdgcn_mfma_f32_16x16x32_bf16(a, bF[t5], accD[mt], 0,0,0);
        }
    }
    #pragma unroll
    for (int t5 = 0; t5 < 5; ++t5) {
        #pragma unroll
        for (int mt = 0; mt < 4; ++mt) {
            short8 a = *(const short8*)(sTh + wbase + mt*288 + aoff[t5]);
            accD[mt] = __builtin_amdgcn_mfma_f32_16x16x32_bf16(a, bH[t5],  accD[mt], 0,0,0);
            accH[mt] = __builtin_amdgcn_mfma_f32_16x16x32_bf16(a, bCh[t5], accH[mt], 0,0,0);
        }
    }
    const int np = (n < 10) ? n : 9;
    const float gDv = sPar[np],    bDv = sPar[10+np];
    const float gCv = sPar[20+np], bCv = sPar[30+np];
    f32x4 msgf[4];
    #pragma unroll
    for (int mt = 0; mt < 4; ++mt)
        #pragma unroll
        for (int j = 0; j < 4; ++j)
            msgf[mt][j] = fmaxf(fmaf(gDv, accD[mt][j], bDv), 0.f);
    __syncthreads();   // all waves done reading sTp0 (f*att)

    // parts, double-buffered: p0 in sTp1; prefetch p_{j+1} into the freed buf
    for (int j = 0; j < nparts; ++j) {
        if (j+1 < nparts)
            dma_tile((j&1) ? sTp1 : sTp0, pArr0 + (size_t)(j+1)*PA, tid, y0, x0);
        const short* cur = (j&1) ? sTp0 : sTp1;
        f32x4 acc[4];
        #pragma unroll
        for (int mt = 0; mt < 4; ++mt) acc[mt] = (f32x4){0,0,0,0};
        #pragma unroll
        for (int t5 = 0; t5 < 5; ++t5) {
            #pragma unroll
            for (int mt = 0; mt < 4; ++mt) {
                short8 a = *(const short8*)(cur + wbase + mt*288 + aoff[t5]);
                acc[mt] = __builtin_amdgcn_mfma_f32_16x16x32_bf16(a, bCp[t5], acc[mt], 0,0,0);
            }
        }
        #pragma unroll
        for (int mt = 0; mt < 4; ++mt)
            #pragma unroll
            for (int jj = 0; jj < 4; ++jj)
                msgf[mt][jj] += fmaxf(fmaf(gCv, accH[mt][jj] + acc[mt][jj], bCv), 0.f);
        __syncthreads();   // cur fully consumed; prefetch drained
    }

    // transpose msg to [pixel][ch]
    if (n < 10) {
        #pragma unroll
        for (int mt = 0; mt < 4; ++mt)
            #pragma unroll
            for (int r2 = 0; r2 < 4; ++r2)
                sMsg[((4*w + mt)*16 + 4*g + r2)*13 + n] = msgf[mt][r2];
    }
    __syncthreads();

    // pointwise ConvGRU epilogue (fp32), one pixel/thread; h from bf16 tile
    {
        int row = tid >> 4, xx = tid & 15;
        int gy = y0 + row, gx = x0 + xx;
        float msg[10], hc[10];
        #pragma unroll
        for (int c = 0; c < 10; ++c) msg[c] = sMsg[tid*13 + c];
        #pragma unroll
        for (int c = 0; c < 10; ++c) hc[c] = b2f(sTh[((row+1)*18 + (xx+1))*16 + c]);

        float g0 = sPar[100], g1 = sPar[101];
        #pragma unroll
        for (int c = 0; c < 10; ++c) {
            g0 = fmaf(sPar[60+c], msg[c], g0);
            g1 = fmaf(sPar[80+c], msg[c], g1);
        }
        #pragma unroll
        for (int c = 0; c < 10; ++c) {
            g0 = fmaf(sPar[70+c], hc[c], g0);
            g1 = fmaf(sPar[90+c], hc[c], g1);
        }
        float r = 1.f / (1.f + expf(-g0));
        float u = 1.f / (1.f + expf(-g1));

        float* op = out + (size_t)(1+half)*BB*CC*HW + (size_t)b*CC*HW + gy*WD + gx;
        #pragma unroll
        for (int o = 0; o < 10; ++o) {
            float s = 0.f;
            const float* wr = &sPar[102 + o*20];
            #pragma unroll
            for (int c = 0; c < 10; ++c) s = fmaf(wr[c], msg[c], s);
            #pragma unroll
            for (int c = 0; c < 10; ++c) s = fmaf(wr[10+c], r*hc[c], s);
            s = fmaf(sPar[40+o], s, sPar[50+o]);
            s = (s > 0.f) ? s : 0.01f*s;
            op[(size_t)o*HW] = (1.f - u)*hc[o] + u*s;
        }
    }
}

// ---------------------------------------------------------------------------
extern "C" void kernel_launch(void* const* d_in, const int* in_sizes, int n_in,
                              void* d_out, int out_size, void* d_ws, size_t ws_size,
                              hipStream_t stream)
{
    const float* f_nodes = (const float*)d_in[0];
    const float* h_nodes = (const float*)d_in[1];
    const float* p_nodes = (const float*)d_in[2];
    const float* w_dmap   = (const float*)d_in[4];
    const float* b_dmap   = (const float*)d_in[5];
    const float* w_decomp = (const float*)d_in[6];
    const float* g_decomp = (const float*)d_in[7];
    const float* be_decomp= (const float*)d_in[8];
    const float* w_cau    = (const float*)d_in[9];
    const float* b_cau    = (const float*)d_in[10];
    const float* w_cal    = (const float*)d_in[11];
    const float* b_cal    = (const float*)d_in[12];
    const float* w_cu     = (const float*)d_in[13];
    const float* g_cu     = (const float*)d_in[14];
    const float* be_cu    = (const float*)d_in[15];
    const float* w_cl     = (const float*)d_in[16];
    const float* g_cl     = (const float*)d_in[17];
    const float* be_cl    = (const float*)d_in[18];
    const float* wg_u     = (const float*)d_in[19];
    const float* bg_u     = (const float*)d_in[20];
    const float* wc_u     = (const float*)d_in[21];
    const float* g_u      = (const float*)d_in[22];
    const float* be_u     = (const float*)d_in[23];
    const float* wg_l     = (const float*)d_in[24];
    const float* bg_l     = (const float*)d_in[25];
    const float* wc_l     = (const float*)d_in[26];
    const float* g_l      = (const float*)d_in[27];
    const float* be_l     = (const float*)d_in[28];

    float* out = (float*)d_out;
    short* ws  = (short*)d_ws;

    prep_kernel<<<dim3((3*NA + 255)/256), dim3(256), 0, stream>>>(
        f_nodes, h_nodes, p_nodes, w_dmap, b_dmap,
        w_cau, b_cau, w_cal, b_cal, out, ws);

    half_kernel<<<dim3(WD/16, WD/16, 16), dim3(256), 0, stream>>>(
        ws, w_decomp, g_decomp, be_decomp,
        w_cu, g_cu, be_cu, w_cl, g_cl, be_cl,
        wg_u, bg_u, wc_u, g_u, be_u,
        wg_l, bg_l, wc_l, g_l, be_l,
        out);
}